// Round 1
// baseline (739.223 us; speedup 1.0000x reference)
//
#include <hip/hip_runtime.h>

#define HD 64
#define VOCAB 64
#define BATCH 256
#define SEQLEN 2048
#define NSTEPS ((SEQLEN - 2) / 2)   // 1023
#define LRc 0.05f

// ---------------- Kernel 1: build the 64x64 encoder table ----------------
// hs[b,l] depends only on seq[b,l] (per-position encoder + LN), so precompute
// enc[v][:] for all 64 vocab entries. One block per token, 64 threads.
__global__ __launch_bounds__(64, 1) void enc_build(
    const float* __restrict__ embed, const float* __restrict__ ffw1,
    const float* __restrict__ ffb1, const float* __restrict__ ffw2,
    const float* __restrict__ ffb2, const float* __restrict__ ln_g,
    const float* __restrict__ ln_b, float* __restrict__ enc) {
  const int v = blockIdx.x, j = threadIdx.x;
  __shared__ float e_s[HD];
  __shared__ float hid_s[2 * HD];
  float e = embed[v * HD + j];
  e_s[j] = e;
  __syncthreads();
  float ha = ffb1[j], hb = ffb1[HD + j];
  #pragma unroll 8
  for (int h = 0; h < HD; ++h) {
    float eh = e_s[h];
    ha = fmaf(ffw1[j * HD + h], eh, ha);
    hb = fmaf(ffw1[(HD + j) * HD + h], eh, hb);
  }
  hid_s[j] = fmaxf(ha, 0.f);
  hid_s[HD + j] = fmaxf(hb, 0.f);
  __syncthreads();
  float ff = ffb2[j];
  #pragma unroll 8
  for (int h2 = 0; h2 < 2 * HD; ++h2) ff = fmaf(ffw2[j * 2 * HD + h2], hid_s[h2], ff);
  float x = e + ff;
  float mu = x;
  #pragma unroll
  for (int m = 1; m < 64; m <<= 1) mu += __shfl_xor(mu, m, 64);
  mu *= (1.f / 64.f);
  float xc = x - mu;
  float var = xc * xc;
  #pragma unroll
  for (int m = 1; m < 64; m <<= 1) var += __shfl_xor(var, m, 64);
  var *= (1.f / 64.f);
  enc[v * HD + j] = xc / sqrtf(var + 1e-5f) * ln_g[j] + ln_b[j];
}

// ---------------- Kernel 2: the sequential TTT scan ----------------
// One wave (64 threads) per batch chain; fast-weight state lives in VGPRs.
// lane l = 32*half + i:
//   W1[c]  = w1[i][32*half + c]    (row i split across the lane pair)
//   W2R[c] = w2[l][c]              (row l -> pred is a lane-local dot)
//   W2T[r] = w2[32*half + r][i]    (half-column i -> dh is a lane-local dot)
// h (32 values) and d (64 values) are broadcast via tiny LDS buffers.
__global__ __launch_bounds__(64, 1) void ttt_run(
    const int* __restrict__ seq, const float* __restrict__ enc,
    const float* __restrict__ w1g, const float* __restrict__ b1g,
    const float* __restrict__ w2g, const float* __restrict__ b2g,
    const float* __restrict__ woutg, const float* __restrict__ boutg,
    float* __restrict__ out) {
  __shared__ float enc_s[VOCAB * HD];   // 16 KB
  __shared__ int   seq_s[SEQLEN];       // 8 KB
  __shared__ float h_s[32];
  __shared__ float d_s[64];
  __shared__ float ctx_s[64];
  const int b = blockIdx.x, l = threadIdx.x;
  const int i = l & 31, half = l >> 5;

  // stage enc table + this chain's token row into LDS (coalesced)
  #pragma unroll
  for (int q = 0; q < 16; ++q)
    ((float4*)enc_s)[l + 64 * q] = ((const float4*)enc)[l + 64 * q];
  const int4* seqg = (const int4*)(seq + b * SEQLEN);
  #pragma unroll
  for (int q = 0; q < 8; ++q)
    ((int4*)seq_s)[l + 64 * q] = seqg[l + 64 * q];

  float W1[32], W2R[32], W2T[32];
  #pragma unroll
  for (int q = 0; q < 8; ++q)
    *(float4*)&W1[4 * q] = *(const float4*)&w1g[i * 64 + half * 32 + 4 * q];
  #pragma unroll
  for (int q = 0; q < 8; ++q)
    *(float4*)&W2R[4 * q] = *(const float4*)&w2g[l * 32 + 4 * q];
  #pragma unroll
  for (int r = 0; r < 32; ++r) W2T[r] = w2g[(half * 32 + r) * 32 + i];
  float b1r = b1g[i];
  float b2r = b2g[l];
  __syncthreads();

  int2 tk = *(const int2*)&seq_s[0];
  float K[32], Hh[32], D[32];
  for (int t = 0; t < NSTEPS; ++t) {
    int2 tknext = *(const int2*)&seq_s[2 * t + 2];  // prefetch next tokens (t=1022 reads [2046..2047], valid)
    // k half-row into registers (broadcast b128 reads), v per-lane
    const float* kr = &enc_s[tk.x * HD + half * 32];
    #pragma unroll
    for (int q = 0; q < 8; ++q) *(float4*)&K[4 * q] = *(const float4*)&kr[4 * q];
    float vv = enc_s[tk.y * HD + l];

    // pre[i] = w1[i,:] @ k + b1[i]  (half-dot + cross-half add)
    float a0 = 0.f, a1 = 0.f, a2 = 0.f, a3 = 0.f;
    #pragma unroll
    for (int c = 0; c < 32; c += 4) {
      a0 = fmaf(W1[c + 0], K[c + 0], a0);
      a1 = fmaf(W1[c + 1], K[c + 1], a1);
      a2 = fmaf(W1[c + 2], K[c + 2], a2);
      a3 = fmaf(W1[c + 3], K[c + 3], a3);
    }
    float part = (a0 + a1) + (a2 + a3);
    float pre = part + __shfl_xor(part, 32, 64) + b1r;
    float h = fmaxf(pre, 0.f);
    h_s[i] = h;  // both pair lanes write the same value
    #pragma unroll
    for (int q = 0; q < 8; ++q) *(float4*)&Hh[4 * q] = *(const float4*)&h_s[4 * q];

    // pred[l] = w2[l,:] @ h + b2[l]  (lane-local)
    float q0 = b2r, q1 = 0.f, q2 = 0.f, q3 = 0.f;
    #pragma unroll
    for (int c = 0; c < 32; c += 4) {
      q0 = fmaf(W2R[c + 0], Hh[c + 0], q0);
      q1 = fmaf(W2R[c + 1], Hh[c + 1], q1);
      q2 = fmaf(W2R[c + 2], Hh[c + 2], q2);
      q3 = fmaf(W2R[c + 3], Hh[c + 3], q3);
    }
    float pred = (q0 + q1) + (q2 + q3);
    float d = (pred - vv) * (2.f / 64.f);
    d_s[l] = d;
    const float* drp = &d_s[half * 32];
    #pragma unroll
    for (int q = 0; q < 8; ++q) *(float4*)&D[4 * q] = *(const float4*)&drp[4 * q];

    // dh[i] = (w2^T @ d)[i] * (pre[i] > 0)  (half-dot + cross-half add)
    float g0 = 0.f, g1 = 0.f, g2 = 0.f, g3 = 0.f;
    #pragma unroll
    for (int r = 0; r < 32; r += 4) {
      g0 = fmaf(W2T[r + 0], D[r + 0], g0);
      g1 = fmaf(W2T[r + 1], D[r + 1], g1);
      g2 = fmaf(W2T[r + 2], D[r + 2], g2);
      g3 = fmaf(W2T[r + 3], D[r + 3], g3);
    }
    float gpart = (g0 + g1) + (g2 + g3);
    float dh = gpart + __shfl_xor(gpart, 32, 64);
    dh = (pre > 0.f) ? dh : 0.f;

    // updates. W2R/W2T share the exact product rounding (t = d*h) so the two
    // register views of w2 stay bitwise identical across all 1023 steps.
    #pragma unroll
    for (int c = 0; c < 32; ++c) {
      float tprod = d * Hh[c];
      W2R[c] = fmaf(-LRc, tprod, W2R[c]);
    }
    #pragma unroll
    for (int r = 0; r < 32; ++r) {
      float tprod = D[r] * h;
      W2T[r] = fmaf(-LRc, tprod, W2T[r]);
    }
    b2r = fmaf(-LRc, d, b2r);
    float LRdh = LRc * dh;
    #pragma unroll
    for (int c = 0; c < 32; ++c) W1[c] = fmaf(-LRdh, K[c], W1[c]);
    b1r -= LRdh;
    tk = tknext;
  }

  // tail: ctx = w2f @ relu(w1f @ enc[seq[L-1]] + b1f) + b2f; out = ctx @ wout^T + bout
  {
    int tok = seq_s[SEQLEN - 1];
    const float* kr = &enc_s[tok * HD + half * 32];
    #pragma unroll
    for (int q = 0; q < 8; ++q) *(float4*)&K[4 * q] = *(const float4*)&kr[4 * q];
    float a0 = 0.f, a1 = 0.f, a2 = 0.f, a3 = 0.f;
    #pragma unroll
    for (int c = 0; c < 32; c += 4) {
      a0 = fmaf(W1[c + 0], K[c + 0], a0);
      a1 = fmaf(W1[c + 1], K[c + 1], a1);
      a2 = fmaf(W1[c + 2], K[c + 2], a2);
      a3 = fmaf(W1[c + 3], K[c + 3], a3);
    }
    float part = (a0 + a1) + (a2 + a3);
    float pre = part + __shfl_xor(part, 32, 64) + b1r;
    float h = fmaxf(pre, 0.f);
    h_s[i] = h;
    #pragma unroll
    for (int q = 0; q < 8; ++q) *(float4*)&Hh[4 * q] = *(const float4*)&h_s[4 * q];
    float q0 = b2r, q1 = 0.f, q2 = 0.f, q3 = 0.f;
    #pragma unroll
    for (int c = 0; c < 32; c += 4) {
      q0 = fmaf(W2R[c + 0], Hh[c + 0], q0);
      q1 = fmaf(W2R[c + 1], Hh[c + 1], q1);
      q2 = fmaf(W2R[c + 2], Hh[c + 2], q2);
      q3 = fmaf(W2R[c + 3], Hh[c + 3], q3);
    }
    ctx_s[l] = (q0 + q1) + (q2 + q3);
    __syncthreads();
    float acc = boutg[l];
    #pragma unroll 8
    for (int jj = 0; jj < 64; ++jj) acc = fmaf(woutg[l * 64 + jj], ctx_s[jj], acc);
    out[b * 64 + l] = acc;
  }
}

extern "C" void kernel_launch(void* const* d_in, const int* in_sizes, int n_in,
                              void* d_out, int out_size, void* d_ws, size_t ws_size,
                              hipStream_t stream) {
  const int*   seq   = (const int*)d_in[0];
  const float* embed = (const float*)d_in[1];
  const float* ffw1  = (const float*)d_in[2];
  const float* ffb1  = (const float*)d_in[3];
  const float* ffw2  = (const float*)d_in[4];
  const float* ffb2  = (const float*)d_in[5];
  const float* ln_g  = (const float*)d_in[6];
  const float* ln_b  = (const float*)d_in[7];
  const float* w1    = (const float*)d_in[8];
  const float* b1    = (const float*)d_in[9];
  const float* w2    = (const float*)d_in[10];
  const float* b2    = (const float*)d_in[11];
  const float* wout  = (const float*)d_in[12];
  const float* bout  = (const float*)d_in[13];
  float* enc = (float*)d_ws;  // 64*64 f32 = 16 KB scratch

  enc_build<<<VOCAB, 64, 0, stream>>>(embed, ffw1, ffb1, ffw2, ffb2, ln_g, ln_b, enc);
  ttt_run<<<BATCH, 64, 0, stream>>>(seq, enc, w1, b1, w2, b2, wout, bout, (float*)d_out);
}

// Round 3
// 489.541 us; speedup vs baseline: 1.5100x; 1.5100x over previous
//
#include <hip/hip_runtime.h>

#define HD 64
#define VOCAB 64
#define BATCH 256
#define SEQLEN 2048
#define NSTEPS ((SEQLEN - 2) / 2)   // 1023
#define LRc 0.05f

// ---------------- Kernel 1: build the 64x64 encoder table ----------------
__global__ __launch_bounds__(64, 1) void enc_build(
    const float* __restrict__ embed, const float* __restrict__ ffw1,
    const float* __restrict__ ffb1, const float* __restrict__ ffw2,
    const float* __restrict__ ffb2, const float* __restrict__ ln_g,
    const float* __restrict__ ln_b, float* __restrict__ enc) {
  const int v = blockIdx.x, j = threadIdx.x;
  __shared__ float e_s[HD];
  __shared__ float hid_s[2 * HD];
  float e = embed[v * HD + j];
  e_s[j] = e;
  __syncthreads();
  float ha = ffb1[j], hb = ffb1[HD + j];
  #pragma unroll 8
  for (int h = 0; h < HD; ++h) {
    float eh = e_s[h];
    ha = fmaf(ffw1[j * HD + h], eh, ha);
    hb = fmaf(ffw1[(HD + j) * HD + h], eh, hb);
  }
  hid_s[j] = fmaxf(ha, 0.f);
  hid_s[HD + j] = fmaxf(hb, 0.f);
  __syncthreads();
  float ff = ffb2[j];
  #pragma unroll 8
  for (int h2 = 0; h2 < 2 * HD; ++h2) ff = fmaf(ffw2[j * 2 * HD + h2], hid_s[h2], ff);
  float x = e + ff;
  float mu = x;
  #pragma unroll
  for (int m = 1; m < 64; m <<= 1) mu += __shfl_xor(mu, m, 64);
  mu *= (1.f / 64.f);
  float xc = x - mu;
  float var = xc * xc;
  #pragma unroll
  for (int m = 1; m < 64; m <<= 1) var += __shfl_xor(var, m, 64);
  var *= (1.f / 64.f);
  enc[v * HD + j] = xc / sqrtf(var + 1e-5f) * ln_g[j] + ln_b[j];
}

// ---------------- Kernel 2: the sequential TTT scan ----------------
// One wave per chain, state in VGPRs. lane l = 32*half + i:
//   W1[c]  = w1[i][32*half + c]
//   W2R[c] = w2[l][c]
//   W2T[r] = w2[32*half + r][i]
// h broadcast via v_readlane (SGPRs); scaled-d broadcast via tiny LDS buffer,
// its latency hidden under the W2R update. K/vv prefetched one step ahead.
__device__ __forceinline__ void ttt_step(
    int l, int half,
    const float* __restrict__ enc_s, const int* __restrict__ seq_s,
    float* __restrict__ sd_s,
    float (&W1)[32], float (&W2R)[32], float (&W2T)[32],
    float& b1r, float& b2r,
    float (&KC)[32], float& vvC, float (&KN)[32], float& vvN,
    int2& tk, int2& tk1, int pidx) {
  // ---- prefetch K/vv for the NEXT step (depends only on tokens) ----
  const float* krn = &enc_s[tk1.x * HD + half * 32];
  #pragma unroll
  for (int q = 0; q < 8; ++q) *(float4*)&KN[4 * q] = *(const float4*)&krn[4 * q];
  vvN = enc_s[tk1.y * HD + l];
  int2 tk2 = *(const int2*)&seq_s[pidx];

  // ---- pre[i] = w1[i,:] @ k + b1[i] ----
  float a0 = 0.f, a1 = 0.f, a2 = 0.f, a3 = 0.f;
  #pragma unroll
  for (int c = 0; c < 32; c += 4) {
    a0 = fmaf(W1[c + 0], KC[c + 0], a0);
    a1 = fmaf(W1[c + 1], KC[c + 1], a1);
    a2 = fmaf(W1[c + 2], KC[c + 2], a2);
    a3 = fmaf(W1[c + 3], KC[c + 3], a3);
  }
  float part = (a0 + a1) + (a2 + a3);
  float pre = part + __shfl_xor(part, 32, 64) + b1r;
  float h = fmaxf(pre, 0.f);

  // ---- broadcast h[0..31] to SGPRs via readlane (no LDS round-trip) ----
  float sh[32];
  #pragma unroll
  for (int c = 0; c < 32; ++c)
    sh[c] = __int_as_float(__builtin_amdgcn_readlane(__float_as_int(h), c));

  // ---- pred[l] = w2[l,:] @ h + b2[l] ----
  float q0 = b2r, q1 = 0.f, q2 = 0.f, q3 = 0.f;
  #pragma unroll
  for (int c = 0; c < 32; c += 4) {
    q0 = fmaf(W2R[c + 0], sh[c + 0], q0);
    q1 = fmaf(W2R[c + 1], sh[c + 1], q1);
    q2 = fmaf(W2R[c + 2], sh[c + 2], q2);
    q3 = fmaf(W2R[c + 3], sh[c + 3], q3);
  }
  float pred = (q0 + q1) + (q2 + q3);

  // sR = -LR * d = (vv - pred) * (2*LR/H)
  float sR = (vvC - pred) * (2.f * LRc / (float)HD);
  sd_s[l] = sR;  // broadcast scaled-d; latency hidden by W2R update below

  // ---- W2R update (independent of the broadcast) ----
  #pragma unroll
  for (int c = 0; c < 32; ++c) W2R[c] = fmaf(sR, sh[c], W2R[c]);
  b2r += sR;

  // ---- read scaled-d for this half ----
  float SD[32];
  const float* drp = &sd_s[half * 32];
  #pragma unroll
  for (int q = 0; q < 8; ++q) *(float4*)&SD[4 * q] = *(const float4*)&drp[4 * q];

  // ---- dh' = -LR * (w2^T @ d)[i], masked by relu ----
  float g0 = 0.f, g1 = 0.f, g2 = 0.f, g3 = 0.f;
  #pragma unroll
  for (int r = 0; r < 32; r += 4) {
    g0 = fmaf(W2T[r + 0], SD[r + 0], g0);
    g1 = fmaf(W2T[r + 1], SD[r + 1], g1);
    g2 = fmaf(W2T[r + 2], SD[r + 2], g2);
    g3 = fmaf(W2T[r + 3], SD[r + 3], g3);
  }
  float gpart = (g0 + g1) + (g2 + g3);
  float dh = gpart + __shfl_xor(gpart, 32, 64);
  dh = (pre > 0.f) ? dh : 0.f;

  // ---- remaining updates ----
  #pragma unroll
  for (int r = 0; r < 32; ++r) W2T[r] = fmaf(SD[r], h, W2T[r]);
  #pragma unroll
  for (int c = 0; c < 32; ++c) W1[c] = fmaf(dh, KC[c], W1[c]);
  b1r += dh;

  tk = tk1;
  tk1 = tk2;
}

__global__ __launch_bounds__(64, 1) void ttt_run(
    const int* __restrict__ seq, const float* __restrict__ enc,
    const float* __restrict__ w1g, const float* __restrict__ b1g,
    const float* __restrict__ w2g, const float* __restrict__ b2g,
    const float* __restrict__ woutg, const float* __restrict__ boutg,
    float* __restrict__ out) {
  __shared__ float enc_s[VOCAB * HD];   // 16 KB
  __shared__ int   seq_s[SEQLEN];       // 8 KB
  __shared__ float sd_s[64];
  __shared__ float ctx_s[64];
  const int b = blockIdx.x, l = threadIdx.x;
  const int i = l & 31, half = l >> 5;

  #pragma unroll
  for (int q = 0; q < 16; ++q)
    ((float4*)enc_s)[l + 64 * q] = ((const float4*)enc)[l + 64 * q];
  const int4* seqg = (const int4*)(seq + b * SEQLEN);
  #pragma unroll
  for (int q = 0; q < 8; ++q)
    ((int4*)seq_s)[l + 64 * q] = seqg[l + 64 * q];

  float W1[32], W2R[32], W2T[32];
  #pragma unroll
  for (int q = 0; q < 8; ++q)
    *(float4*)&W1[4 * q] = *(const float4*)&w1g[i * 64 + half * 32 + 4 * q];
  #pragma unroll
  for (int q = 0; q < 8; ++q)
    *(float4*)&W2R[4 * q] = *(const float4*)&w2g[l * 32 + 4 * q];
  #pragma unroll
  for (int r = 0; r < 32; ++r) W2T[r] = w2g[(half * 32 + r) * 32 + i];
  float b1r = b1g[i];
  float b2r = b2g[l];
  __syncthreads();

  int2 tk  = *(const int2*)&seq_s[0];
  int2 tk1 = *(const int2*)&seq_s[2];
  float KA[32], KB[32], vvA, vvB;
  {
    const float* kr = &enc_s[tk.x * HD + half * 32];
    #pragma unroll
    for (int q = 0; q < 8; ++q) *(float4*)&KA[4 * q] = *(const float4*)&kr[4 * q];
    vvA = enc_s[tk.y * HD + l];
  }

  // 511 unrolled pairs (1022 steps) + 1 tail step = 1023
  for (int s = 0; s < NSTEPS - 1; s += 2) {
    int p0 = 2 * s + 4;  if (p0 > 2046) p0 = 2046;
    int p1 = 2 * s + 6;  if (p1 > 2046) p1 = 2046;
    ttt_step(l, half, enc_s, seq_s, sd_s, W1, W2R, W2T, b1r, b2r,
             KA, vvA, KB, vvB, tk, tk1, p0);
    ttt_step(l, half, enc_s, seq_s, sd_s, W1, W2R, W2T, b1r, b2r,
             KB, vvB, KA, vvA, tk, tk1, p1);
  }
  ttt_step(l, half, enc_s, seq_s, sd_s, W1, W2R, W2T, b1r, b2r,
           KA, vvA, KB, vvB, tk, tk1, 2046 /*clamped; result unused*/);

  // ---- tail: ctx = w2f @ relu(w1f @ enc[seq[L-1]] + b1f) + b2f ----
  {
    int tok = seq_s[SEQLEN - 1];
    float K[32];
    const float* kr = &enc_s[tok * HD + half * 32];
    #pragma unroll
    for (int q = 0; q < 8; ++q) *(float4*)&K[4 * q] = *(const float4*)&kr[4 * q];
    float a0 = 0.f, a1 = 0.f, a2 = 0.f, a3 = 0.f;
    #pragma unroll
    for (int c = 0; c < 32; c += 4) {
      a0 = fmaf(W1[c + 0], K[c + 0], a0);
      a1 = fmaf(W1[c + 1], K[c + 1], a1);
      a2 = fmaf(W1[c + 2], K[c + 2], a2);
      a3 = fmaf(W1[c + 3], K[c + 3], a3);
    }
    float part = (a0 + a1) + (a2 + a3);
    float pre = part + __shfl_xor(part, 32, 64) + b1r;
    float h = fmaxf(pre, 0.f);
    float sh[32];
    #pragma unroll
    for (int c = 0; c < 32; ++c)
      sh[c] = __int_as_float(__builtin_amdgcn_readlane(__float_as_int(h), c));
    float q0 = b2r, q1 = 0.f, q2 = 0.f, q3 = 0.f;
    #pragma unroll
    for (int c = 0; c < 32; c += 4) {
      q0 = fmaf(W2R[c + 0], sh[c + 0], q0);
      q1 = fmaf(W2R[c + 1], sh[c + 1], q1);
      q2 = fmaf(W2R[c + 2], sh[c + 2], q2);
      q3 = fmaf(W2R[c + 3], sh[c + 3], q3);
    }
    ctx_s[l] = (q0 + q1) + (q2 + q3);
    __syncthreads();
    float acc = boutg[l];
    #pragma unroll 8
    for (int jj = 0; jj < 64; ++jj) acc = fmaf(woutg[l * 64 + jj], ctx_s[jj], acc);
    out[b * 64 + l] = acc;
  }
}

extern "C" void kernel_launch(void* const* d_in, const int* in_sizes, int n_in,
                              void* d_out, int out_size, void* d_ws, size_t ws_size,
                              hipStream_t stream) {
  const int*   seq   = (const int*)d_in[0];
  const float* embed = (const float*)d_in[1];
  const float* ffw1  = (const float*)d_in[2];
  const float* ffb1  = (const float*)d_in[3];
  const float* ffw2  = (const float*)d_in[4];
  const float* ffb2  = (const float*)d_in[5];
  const float* ln_g  = (const float*)d_in[6];
  const float* ln_b  = (const float*)d_in[7];
  const float* w1    = (const float*)d_in[8];
  const float* b1    = (const float*)d_in[9];
  const float* w2    = (const float*)d_in[10];
  const float* b2    = (const float*)d_in[11];
  const float* wout  = (const float*)d_in[12];
  const float* bout  = (const float*)d_in[13];
  float* enc = (float*)d_ws;  // 64*64 f32 = 16 KB scratch

  enc_build<<<VOCAB, 64, 0, stream>>>(embed, ffw1, ffb1, ffw2, ffb2, ln_g, ln_b, enc);
  ttt_run<<<BATCH, 64, 0, stream>>>(seq, enc, w1, b1, w2, b2, wout, bout, (float*)d_out);
}